// Round 1
// baseline (5002.760 us; speedup 1.0000x reference)
//
#include <hip/hip_runtime.h>
#include <hip/hip_bf16.h>

// 3-layer GCN: per layer  h = X@W ; a = scatter_add(h[src]*dinv[s]*dinv[d] -> dst)
//                         out = a + h*dinv^2 + b ; relu (layers 1,2) ; log_softmax (layer 3)

// ---------------- degree ----------------
__global__ void deg_count(const int* __restrict__ dst, int E, float* __restrict__ deg) {
    int i = blockIdx.x * blockDim.x + threadIdx.x;
    if (i < E) atomicAdd(&deg[dst[i]], 1.0f);
}

__global__ void deg_to_dinv(float* __restrict__ deg, int n) {
    int i = blockIdx.x * blockDim.x + threadIdx.x;
    if (i < n) {
        float x = 1.0f + deg[i];
        float r = rsqrtf(x);
        r = r * (1.5f - 0.5f * x * r * r);   // Newton refine to full f32 precision
        deg[i] = r;
    }
}

// ---------------- small GEMM: H[n,FOUT] = X[n,FIN] @ W[FIN,FOUT] ----------------
// 256 threads; each thread computes 4 consecutive output cols for one row.
template<int FIN, int FOUT, int ROWS>
__global__ __launch_bounds__(256) void gemm_small(const float* __restrict__ X,
                                                  const float* __restrict__ W,
                                                  float* __restrict__ H, int n) {
    constexpr int NCG = FOUT / 4;            // col groups of 4; ROWS = 256/NCG
    __shared__ float Ws[FIN * FOUT];
    __shared__ float Xs[ROWS][FIN + 1];      // +1 pad: kills 8-way bank conflict on Xs[r][k]
    const int row0 = blockIdx.x * ROWS;

    for (int i = threadIdx.x; i < FIN * FOUT; i += 256) Ws[i] = W[i];
    for (int i = threadIdx.x; i < ROWS * FIN; i += 256) {
        int r = i / FIN, k = i - r * FIN;
        int gr = row0 + r;
        Xs[r][k] = (gr < n) ? X[(size_t)gr * FIN + k] : 0.0f;
    }
    __syncthreads();

    const int r  = threadIdx.x / NCG;
    const int cg = threadIdx.x % NCG;
    float4 acc = {0.f, 0.f, 0.f, 0.f};
    #pragma unroll 4
    for (int k = 0; k < FIN; ++k) {
        float xv = Xs[r][k];
        const float4 w4 = *reinterpret_cast<const float4*>(&Ws[k * FOUT + cg * 4]);
        acc.x += xv * w4.x; acc.y += xv * w4.y;
        acc.z += xv * w4.z; acc.w += xv * w4.w;
    }
    const int gr = row0 + r;
    if (gr < n)
        *reinterpret_cast<float4*>(&H[(size_t)gr * FOUT + cg * 4]) = acc;
}

// ---------------- edge scatter: a[dst] += h[src] * dinv[src]*dinv[dst] ----------------
// One thread per (edge, quad-of-4-features): idx/dinv loads broadcast within the
// F/4-thread group; gather coalesces into contiguous row segments.
template<int F>
__global__ void edge_prop(const int* __restrict__ src, const int* __restrict__ dst,
                          const float* __restrict__ dinv, const float* __restrict__ h,
                          float* __restrict__ out, int E) {
    constexpr int Q = F / 4;
    int gi = blockIdx.x * blockDim.x + threadIdx.x;
    int e = gi / Q;
    if (e >= E) return;
    int q = gi - e * Q;
    int s = src[e], d = dst[e];
    float w = dinv[s] * dinv[d];
    const float4 hv = *reinterpret_cast<const float4*>(&h[s * F + q * 4]);
    float* o = &out[d * F + q * 4];
    atomicAdd(o + 0, hv.x * w);
    atomicAdd(o + 1, hv.y * w);
    atomicAdd(o + 2, hv.z * w);
    atomicAdd(o + 3, hv.w * w);
}

// ---------------- combine: a = [relu](a + h*dinv^2 + b) ----------------
template<int F, bool RELU>
__global__ void combine(float* __restrict__ a, const float* __restrict__ h,
                        const float* __restrict__ dinv, const float* __restrict__ b, int n) {
    constexpr int Q = F / 4;
    int gi = blockIdx.x * blockDim.x + threadIdx.x;
    int node = gi / Q;
    if (node >= n) return;
    int q = gi - node * Q;
    float di = dinv[node];
    float sc = di * di;
    float4 av = *reinterpret_cast<const float4*>(&a[node * F + q * 4]);
    const float4 hv = *reinterpret_cast<const float4*>(&h[node * F + q * 4]);
    const float4 bv = *reinterpret_cast<const float4*>(&b[q * 4]);
    float4 v;
    v.x = av.x + hv.x * sc + bv.x;
    v.y = av.y + hv.y * sc + bv.y;
    v.z = av.z + hv.z * sc + bv.z;
    v.w = av.w + hv.w * sc + bv.w;
    if (RELU) {
        v.x = fmaxf(v.x, 0.f); v.y = fmaxf(v.y, 0.f);
        v.z = fmaxf(v.z, 0.f); v.w = fmaxf(v.w, 0.f);
    }
    *reinterpret_cast<float4*>(&a[node * F + q * 4]) = v;
}

// ---------------- final: combine (F=16, no relu) + log_softmax ----------------
__global__ void final_ls(const float* __restrict__ a, const float* __restrict__ h,
                         const float* __restrict__ dinv, const float* __restrict__ b,
                         float* __restrict__ out, int n) {
    int node = blockIdx.x * blockDim.x + threadIdx.x;
    if (node >= n) return;
    float di = dinv[node];
    float sc = di * di;
    float v[16];
    #pragma unroll
    for (int q = 0; q < 4; ++q) {
        const float4 av = *reinterpret_cast<const float4*>(&a[node * 16 + q * 4]);
        const float4 hv = *reinterpret_cast<const float4*>(&h[node * 16 + q * 4]);
        const float4 bv = *reinterpret_cast<const float4*>(&b[q * 4]);
        v[q * 4 + 0] = av.x + hv.x * sc + bv.x;
        v[q * 4 + 1] = av.y + hv.y * sc + bv.y;
        v[q * 4 + 2] = av.z + hv.z * sc + bv.z;
        v[q * 4 + 3] = av.w + hv.w * sc + bv.w;
    }
    float m = v[0];
    #pragma unroll
    for (int i = 1; i < 16; ++i) m = fmaxf(m, v[i]);
    float ssum = 0.f;
    #pragma unroll
    for (int i = 0; i < 16; ++i) ssum += __expf(v[i] - m);
    float lse = m + __logf(ssum);
    #pragma unroll
    for (int q = 0; q < 4; ++q) {
        float4 o;
        o.x = v[q * 4 + 0] - lse; o.y = v[q * 4 + 1] - lse;
        o.z = v[q * 4 + 2] - lse; o.w = v[q * 4 + 3] - lse;
        *reinterpret_cast<float4*>(&out[node * 16 + q * 4]) = o;
    }
}

extern "C" void kernel_launch(void* const* d_in, const int* in_sizes, int n_in,
                              void* d_out, int out_size, void* d_ws, size_t ws_size,
                              hipStream_t stream) {
    const float* x  = (const float*)d_in[0];
    const int*   ei = (const int*)d_in[1];
    const float* W1 = (const float*)d_in[2];
    const float* b1 = (const float*)d_in[3];
    const float* W2 = (const float*)d_in[4];
    const float* b2 = (const float*)d_in[5];
    const float* W3 = (const float*)d_in[6];
    const float* b3 = (const float*)d_in[7];
    float* out = (float*)d_out;

    const int n = in_sizes[0] / 256;     // 100000
    const int E = in_sizes[1] / 2;       // 3200000
    const int* src = ei;
    const int* dst = ei + E;

    // workspace layout (floats); h3/a3 alias h1/a1 (dead by layer-3 time)
    float* ws   = (float*)d_ws;
    float* dinv = ws;                    // n
    float* h1   = dinv + n;              // n*32
    float* a1   = h1 + (size_t)n * 32;   // n*32
    float* h2   = a1 + (size_t)n * 32;   // n*64
    float* a2   = h2 + (size_t)n * 64;   // n*64
    float* h3   = h1;                    // n*16 (reuse)
    float* a3   = a1;                    // n*16 (reuse)

    const int T = 256;

    // degrees -> dinv
    hipMemsetAsync(dinv, 0, (size_t)n * 4, stream);
    deg_count<<<(E + T - 1) / T, T, 0, stream>>>(dst, E, dinv);
    deg_to_dinv<<<(n + T - 1) / T, T, 0, stream>>>(dinv, n);

    // ---- layer 1: 256 -> 32, relu ----
    gemm_small<256, 32, 32><<<(n + 31) / 32, T, 0, stream>>>(x, W1, h1, n);
    hipMemsetAsync(a1, 0, (size_t)n * 32 * 4, stream);
    edge_prop<32><<<(E * 8 + T - 1) / T, T, 0, stream>>>(src, dst, dinv, h1, a1, E);
    combine<32, true><<<(n * 8 + T - 1) / T, T, 0, stream>>>(a1, h1, dinv, b1, n);

    // ---- layer 2: 32 -> 64, relu ----
    gemm_small<32, 64, 16><<<(n + 15) / 16, T, 0, stream>>>(a1, W2, h2, n);
    hipMemsetAsync(a2, 0, (size_t)n * 64 * 4, stream);
    edge_prop<64><<<(E * 16 + T - 1) / T, T, 0, stream>>>(src, dst, dinv, h2, a2, E);
    combine<64, true><<<(n * 16 + T - 1) / T, T, 0, stream>>>(a2, h2, dinv, b2, n);

    // ---- layer 3: 64 -> 16, log_softmax ----
    gemm_small<64, 16, 64><<<(n + 63) / 64, T, 0, stream>>>(a2, W3, h3, n);
    hipMemsetAsync(a3, 0, (size_t)n * 16 * 4, stream);
    edge_prop<16><<<(E * 4 + T - 1) / T, T, 0, stream>>>(src, dst, dinv, h3, a3, E);
    final_ls<<<(n + T - 1) / T, T, 0, stream>>>(a3, h3, dinv, b3, out, n);
}

// Round 2
// 951.421 us; speedup vs baseline: 5.2582x; 5.2582x over previous
//
#include <hip/hip_runtime.h>
#include <hip/hip_bf16.h>

// 3-layer GCN, CSR-gather formulation (no float atomics):
//   cnt[d]   = #in-edges (histogram)          -> dinv = rsqrt(1+cnt)
//   CSR(dst) = rowptr + csr_src               (counting sort, built once per launch)
//   per layer: g = (X@W) * dinv[row]          (GEMM epilogue scale)
//              out[d] = act( dinv[d]*(sum_{e:dst=d} g[src[e]] + g[d]) + b )

// ---------------- CSR build ----------------
__global__ void hist_kernel(const int* __restrict__ dst, int E, int* __restrict__ cnt) {
    int i = blockIdx.x * blockDim.x + threadIdx.x;
    if (i < E) atomicAdd(&cnt[dst[i]], 1);
}

__global__ void scan_block_sums(const int* __restrict__ cnt, int n, int* __restrict__ bsum) {
    __shared__ int s[256];
    int i = blockIdx.x * 256 + threadIdx.x;
    s[threadIdx.x] = (i < n) ? cnt[i] : 0;
    __syncthreads();
    for (int o = 128; o > 0; o >>= 1) {
        if (threadIdx.x < o) s[threadIdx.x] += s[threadIdx.x + o];
        __syncthreads();
    }
    if (threadIdx.x == 0) bsum[blockIdx.x] = s[0];
}

__global__ void scan_small(int* __restrict__ bsum, int nb) {   // 1 block, 512 threads
    __shared__ int s[512];
    int v = (threadIdx.x < nb) ? bsum[threadIdx.x] : 0;
    s[threadIdx.x] = v;
    __syncthreads();
    for (int o = 1; o < 512; o <<= 1) {
        int t = (threadIdx.x >= (unsigned)o) ? s[threadIdx.x - o] : 0;
        __syncthreads();
        s[threadIdx.x] += t;
        __syncthreads();
    }
    if (threadIdx.x < nb) bsum[threadIdx.x] = s[threadIdx.x] - v;  // exclusive
}

__global__ void scan_write(const int* __restrict__ cnt, int n, const int* __restrict__ bsum,
                           int* __restrict__ rowptr, int* __restrict__ fill,
                           float* __restrict__ dinv) {
    __shared__ int s[256];
    int i = blockIdx.x * 256 + threadIdx.x;
    int v = (i < n) ? cnt[i] : 0;
    s[threadIdx.x] = v;
    __syncthreads();
    for (int o = 1; o < 256; o <<= 1) {
        int t = (threadIdx.x >= (unsigned)o) ? s[threadIdx.x - o] : 0;
        __syncthreads();
        s[threadIdx.x] += t;
        __syncthreads();
    }
    if (i < n) {
        int excl = bsum[blockIdx.x] + s[threadIdx.x] - v;
        rowptr[i] = excl;
        fill[i]   = excl;
        float x = 1.0f + (float)v;
        float r = rsqrtf(x);
        r = r * (1.5f - 0.5f * x * r * r);   // Newton refine to full f32 precision
        dinv[i] = r;
        if (i == n - 1) rowptr[n] = excl + v;   // = E
    }
}

__global__ void csr_scatter(const int* __restrict__ src, const int* __restrict__ dst, int E,
                            int* __restrict__ fill, int* __restrict__ csr_src) {
    int e = blockIdx.x * blockDim.x + threadIdx.x;
    if (e < E) {
        int p = atomicAdd(&fill[dst[e]], 1);
        csr_src[p] = src[e];
    }
}

// ---------------- small GEMM: G[n,FOUT] = (X[n,FIN] @ W[FIN,FOUT]) * dinv[row] ----------------
template<int FIN, int FOUT, int ROWS>
__global__ __launch_bounds__(256) void gemm_small(const float* __restrict__ X,
                                                  const float* __restrict__ W,
                                                  const float* __restrict__ dinv,
                                                  float* __restrict__ G, int n) {
    constexpr int NCG = FOUT / 4;            // col groups of 4; ROWS = 256/NCG
    __shared__ float Ws[FIN * FOUT];
    __shared__ float Xs[ROWS][FIN + 1];      // +1 pad: kills bank conflict on Xs[r][k]
    const int row0 = blockIdx.x * ROWS;

    for (int i = threadIdx.x; i < FIN * FOUT; i += 256) Ws[i] = W[i];
    for (int i = threadIdx.x; i < ROWS * FIN; i += 256) {
        int r = i / FIN, k = i - r * FIN;
        int gr = row0 + r;
        Xs[r][k] = (gr < n) ? X[(size_t)gr * FIN + k] : 0.0f;
    }
    __syncthreads();

    const int r  = threadIdx.x / NCG;
    const int cg = threadIdx.x % NCG;
    float4 acc = {0.f, 0.f, 0.f, 0.f};
    #pragma unroll 4
    for (int k = 0; k < FIN; ++k) {
        float xv = Xs[r][k];
        const float4 w4 = *reinterpret_cast<const float4*>(&Ws[k * FOUT + cg * 4]);
        acc.x += xv * w4.x; acc.y += xv * w4.y;
        acc.z += xv * w4.z; acc.w += xv * w4.w;
    }
    const int gr = row0 + r;
    if (gr < n) {
        float di = dinv[gr];
        acc.x *= di; acc.y *= di; acc.z *= di; acc.w *= di;
        *reinterpret_cast<float4*>(&G[(size_t)gr * FOUT + cg * 4]) = acc;
    }
}

// ---------------- SpMM gather: a[d] = sum_{e in CSR row d} g[src[e]]  (+fused epilogue) ----------------
// F lanes per node; csr_src/rowptr reads broadcast within the lane group; no atomics.
template<int F, bool FUSE, bool RELU>
__global__ void spmm(const int* __restrict__ rowptr, const int* __restrict__ csr_src,
                     const float* __restrict__ g, const float* __restrict__ dinv,
                     const float* __restrict__ b, float* __restrict__ out, int n) {
    int gi = blockIdx.x * blockDim.x + threadIdx.x;
    int node = gi / F;
    int lane = gi % F;
    if (node >= n) return;
    int beg = rowptr[node], end = rowptr[node + 1];
    float acc = 0.f;
    int j = beg;
    for (; j + 3 < end; j += 4) {          // 4 independent gathers in flight
        int s0 = csr_src[j], s1 = csr_src[j + 1], s2 = csr_src[j + 2], s3 = csr_src[j + 3];
        acc += g[(size_t)s0 * F + lane];
        acc += g[(size_t)s1 * F + lane];
        acc += g[(size_t)s2 * F + lane];
        acc += g[(size_t)s3 * F + lane];
    }
    for (; j < end; ++j) acc += g[(size_t)csr_src[j] * F + lane];
    if (FUSE) {
        float v = dinv[node] * (acc + g[(size_t)node * F + lane]) + b[lane];
        if (RELU) v = fmaxf(v, 0.f);
        out[(size_t)node * F + lane] = v;
    } else {
        out[(size_t)node * F + lane] = acc;
    }
}

// ---------------- final: out = dinv*(a+g)+b, then log_softmax over 16 cols ----------------
__global__ void final_ls(const float* __restrict__ a, const float* __restrict__ g,
                         const float* __restrict__ dinv, const float* __restrict__ b,
                         float* __restrict__ out, int n) {
    int node = blockIdx.x * blockDim.x + threadIdx.x;
    if (node >= n) return;
    float di = dinv[node];
    float v[16];
    #pragma unroll
    for (int q = 0; q < 4; ++q) {
        const float4 av = *reinterpret_cast<const float4*>(&a[(size_t)node * 16 + q * 4]);
        const float4 gv = *reinterpret_cast<const float4*>(&g[(size_t)node * 16 + q * 4]);
        const float4 bv = *reinterpret_cast<const float4*>(&b[q * 4]);
        v[q * 4 + 0] = di * (av.x + gv.x) + bv.x;
        v[q * 4 + 1] = di * (av.y + gv.y) + bv.y;
        v[q * 4 + 2] = di * (av.z + gv.z) + bv.z;
        v[q * 4 + 3] = di * (av.w + gv.w) + bv.w;
    }
    float m = v[0];
    #pragma unroll
    for (int i = 1; i < 16; ++i) m = fmaxf(m, v[i]);
    float ssum = 0.f;
    #pragma unroll
    for (int i = 0; i < 16; ++i) ssum += __expf(v[i] - m);
    float lse = m + __logf(ssum);
    #pragma unroll
    for (int q = 0; q < 4; ++q) {
        float4 o;
        o.x = v[q * 4 + 0] - lse; o.y = v[q * 4 + 1] - lse;
        o.z = v[q * 4 + 2] - lse; o.w = v[q * 4 + 3] - lse;
        *reinterpret_cast<float4*>(&out[(size_t)node * 16 + q * 4]) = o;
    }
}

extern "C" void kernel_launch(void* const* d_in, const int* in_sizes, int n_in,
                              void* d_out, int out_size, void* d_ws, size_t ws_size,
                              hipStream_t stream) {
    const float* x  = (const float*)d_in[0];
    const int*   ei = (const int*)d_in[1];
    const float* W1 = (const float*)d_in[2];
    const float* b1 = (const float*)d_in[3];
    const float* W2 = (const float*)d_in[4];
    const float* b2 = (const float*)d_in[5];
    const float* W3 = (const float*)d_in[6];
    const float* b3 = (const float*)d_in[7];
    float* out = (float*)d_out;

    const int n = in_sizes[0] / 256;     // 100000
    const int E = in_sizes[1] / 2;       // 3200000
    const int* src = ei;
    const int* dst = ei + E;

    const int NP = ((n + 256) + 255) / 256 * 256;   // padded slots (>= n+1), keeps 16B alignment

    // workspace layout (4-byte units, all 256-element aligned regions)
    int*   cnt     = (int*)d_ws;              // NP
    int*   rowptr  = cnt + NP;                // NP (uses n+1)
    int*   fill    = rowptr + NP;             // NP
    int*   bsum    = fill + NP;               // 512
    float* dinv    = (float*)(bsum + 512);    // NP
    int*   csr_src = (int*)(dinv + NP);       // E
    float* g1      = (float*)(csr_src + E);   // n*32
    float* a1      = g1 + (size_t)n * 32;     // n*32
    float* g2      = a1 + (size_t)n * 32;     // n*64
    float* a2      = g2 + (size_t)n * 64;     // n*64
    float* g3      = g1;                      // n*16 (reuse)
    float* a3      = a1;                      // n*16 (reuse)

    const int T = 256;
    const int nb = (n + 255) / 256;

    // ---- CSR build + dinv ----
    hipMemsetAsync(cnt, 0, (size_t)NP * 4, stream);
    hist_kernel<<<(E + T - 1) / T, T, 0, stream>>>(dst, E, cnt);
    scan_block_sums<<<nb, 256, 0, stream>>>(cnt, n, bsum);
    scan_small<<<1, 512, 0, stream>>>(bsum, nb);
    scan_write<<<nb, 256, 0, stream>>>(cnt, n, bsum, rowptr, fill, dinv);
    csr_scatter<<<(E + T - 1) / T, T, 0, stream>>>(src, dst, E, fill, csr_src);

    // ---- layer 1: 256 -> 32, relu ----
    gemm_small<256, 32, 32><<<(n + 31) / 32, T, 0, stream>>>(x, W1, dinv, g1, n);
    spmm<32, true, true><<<((size_t)n * 32 + T - 1) / T, T, 0, stream>>>(rowptr, csr_src, g1, dinv, b1, a1, n);

    // ---- layer 2: 32 -> 64, relu ----
    gemm_small<32, 64, 16><<<(n + 15) / 16, T, 0, stream>>>(a1, W2, dinv, g2, n);
    spmm<64, true, true><<<((size_t)n * 64 + T - 1) / T, T, 0, stream>>>(rowptr, csr_src, g2, dinv, b2, a2, n);

    // ---- layer 3: 64 -> 16, log_softmax ----
    gemm_small<64, 16, 64><<<(n + 63) / 64, T, 0, stream>>>(a2, W3, dinv, g3, n);
    spmm<16, false, false><<<((size_t)n * 16 + T - 1) / T, T, 0, stream>>>(rowptr, csr_src, g3, dinv, b3, a3, n);
    final_ls<<<(n + T - 1) / T, T, 0, stream>>>(a3, g3, dinv, b3, out, n);
}

// Round 3
// 865.526 us; speedup vs baseline: 5.7800x; 1.0992x over previous
//
#include <hip/hip_runtime.h>
#include <hip/hip_bf16.h>

// 3-layer GCN, CSR-gather formulation (no float atomics).
// CSR build = two-level counting sort:
//   p1: bucket edges by dst>>6 (dense appends -> low write amplification)
//   p2: per-bucket LDS histogram + LDS-cursor scatter into contiguous csr ranges

#define BSHIFT 6
#define BWIDTH 64                 // nodes per bucket
#define MAXNB  2048               // supports n <= 131072

// ---------------- pass 1: bucket histogram (LDS-local, few global atomics) ----------------
__global__ void p1_hist(const int* __restrict__ dst, int E, int* __restrict__ bcnt, int NB) {
    __shared__ int h[MAXNB];
    for (int i = threadIdx.x; i < NB; i += blockDim.x) h[i] = 0;
    __syncthreads();
    for (int i = blockIdx.x * blockDim.x + threadIdx.x; i < E; i += gridDim.x * blockDim.x)
        atomicAdd(&h[dst[i] >> BSHIFT], 1);
    __syncthreads();
    for (int i = threadIdx.x; i < NB; i += blockDim.x)
        if (h[i]) atomicAdd(&bcnt[i], h[i]);
}

// 1 block, 1024 threads: exclusive scan of bucket counts; init padded fill cursors
__global__ void p1_scan(const int* __restrict__ bcnt, int NB, int E,
                        int* __restrict__ bbase, int* __restrict__ bfill) {
    __shared__ int s[1024];
    __shared__ int carry;
    if (threadIdx.x == 0) carry = 0;
    __syncthreads();
    for (int base = 0; base < NB; base += 1024) {
        int idx = base + threadIdx.x;
        int v = (idx < NB) ? bcnt[idx] : 0;
        s[threadIdx.x] = v;
        __syncthreads();
        for (int o = 1; o < 1024; o <<= 1) {
            int t = (threadIdx.x >= (unsigned)o) ? s[threadIdx.x - o] : 0;
            __syncthreads();
            s[threadIdx.x] += t;
            __syncthreads();
        }
        int excl = carry + s[threadIdx.x] - v;
        if (idx < NB) { bbase[idx] = excl; bfill[idx * 16] = excl; }  // fill padded: 1 counter / 64B line
        __syncthreads();
        if (threadIdx.x == 0) carry += s[1023];
        __syncthreads();
    }
    if (threadIdx.x == 0) bbase[NB] = E;
}

__global__ void p1_scatter(const int* __restrict__ src, const int* __restrict__ dst, int E,
                           int* __restrict__ bfill, int2* __restrict__ ebuf) {
    int i = blockIdx.x * blockDim.x + threadIdx.x;
    if (i >= E) return;
    int s = src[i], d = dst[i];
    int p = atomicAdd(&bfill[(d >> BSHIFT) * 16], 1);   // dense sequential appends per bucket
    ebuf[p] = make_int2(s, d);
}

// ---------------- pass 2: per-bucket node histogram (writes cnt) ----------------
__global__ void p2_hist(const int2* __restrict__ ebuf, const int* __restrict__ bbase,
                        int* __restrict__ cnt, int n) {
    int b = blockIdx.x;
    __shared__ int h[BWIDTH];
    if (threadIdx.x < BWIDTH) h[threadIdx.x] = 0;
    __syncthreads();
    int beg = bbase[b], end = bbase[b + 1];
    for (int i = beg + threadIdx.x; i < end; i += blockDim.x)
        atomicAdd(&h[ebuf[i].y & (BWIDTH - 1)], 1);
    __syncthreads();
    int node = b * BWIDTH + threadIdx.x;
    if (threadIdx.x < BWIDTH && node < n) cnt[node] = h[threadIdx.x];
}

// ---------------- node-level scan: cnt -> rowptr, dinv ----------------
__global__ void scan_block_sums(const int* __restrict__ cnt, int n, int* __restrict__ bsum) {
    __shared__ int s[256];
    int i = blockIdx.x * 256 + threadIdx.x;
    s[threadIdx.x] = (i < n) ? cnt[i] : 0;
    __syncthreads();
    for (int o = 128; o > 0; o >>= 1) {
        if (threadIdx.x < o) s[threadIdx.x] += s[threadIdx.x + o];
        __syncthreads();
    }
    if (threadIdx.x == 0) bsum[blockIdx.x] = s[0];
}

__global__ void scan_small(int* __restrict__ bsum, int nb) {   // 1 block, 512 threads
    __shared__ int s[512];
    int v = (threadIdx.x < (unsigned)nb) ? bsum[threadIdx.x] : 0;
    s[threadIdx.x] = v;
    __syncthreads();
    for (int o = 1; o < 512; o <<= 1) {
        int t = (threadIdx.x >= (unsigned)o) ? s[threadIdx.x - o] : 0;
        __syncthreads();
        s[threadIdx.x] += t;
        __syncthreads();
    }
    if (threadIdx.x < (unsigned)nb) bsum[threadIdx.x] = s[threadIdx.x] - v;  // exclusive
}

__global__ void scan_write(const int* __restrict__ cnt, int n, const int* __restrict__ bsum,
                           int* __restrict__ rowptr, float* __restrict__ dinv) {
    __shared__ int s[256];
    int i = blockIdx.x * 256 + threadIdx.x;
    int v = (i < n) ? cnt[i] : 0;
    s[threadIdx.x] = v;
    __syncthreads();
    for (int o = 1; o < 256; o <<= 1) {
        int t = (threadIdx.x >= (unsigned)o) ? s[threadIdx.x - o] : 0;
        __syncthreads();
        s[threadIdx.x] += t;
        __syncthreads();
    }
    if (i < n) {
        int excl = bsum[blockIdx.x] + s[threadIdx.x] - v;
        rowptr[i] = excl;
        float x = 1.0f + (float)v;
        float r = rsqrtf(x);
        r = r * (1.5f - 0.5f * x * r * r);   // Newton refine to full f32 precision
        dinv[i] = r;
        if (i == n - 1) rowptr[n] = excl + v;   // = E
    }
}

// ---------------- pass 2 scatter: contiguous per-bucket csr_src ranges ----------------
__global__ void p2_scatter(const int2* __restrict__ ebuf, const int* __restrict__ bbase,
                           const int* __restrict__ rowptr, int* __restrict__ csr_src, int n) {
    int b = blockIdx.x;
    __shared__ int cur[BWIDTH];
    int node = b * BWIDTH + threadIdx.x;
    if (threadIdx.x < BWIDTH) cur[threadIdx.x] = (node < n) ? rowptr[node] : 0;
    __syncthreads();
    int beg = bbase[b], end = bbase[b + 1];
    for (int i = beg + threadIdx.x; i < end; i += blockDim.x) {
        int2 e = ebuf[i];
        int p = atomicAdd(&cur[e.y & (BWIDTH - 1)], 1);   // LDS cursor, cheap
        csr_src[p] = e.x;                                 // lands in ~8KB bucket-local range
    }
}

// ---------------- small GEMM: G[n,FOUT] = (X[n,FIN] @ W[FIN,FOUT]) * dinv[row] ----------------
template<int FIN, int FOUT, int ROWS>
__global__ __launch_bounds__(256) void gemm_small(const float* __restrict__ X,
                                                  const float* __restrict__ W,
                                                  const float* __restrict__ dinv,
                                                  float* __restrict__ G, int n) {
    constexpr int NCG = FOUT / 4;            // col groups of 4; ROWS = 256/NCG
    __shared__ float Ws[FIN * FOUT];
    __shared__ float Xs[ROWS][FIN + 1];      // +1 pad: kills bank conflict on Xs[r][k]
    const int row0 = blockIdx.x * ROWS;

    for (int i = threadIdx.x; i < FIN * FOUT; i += 256) Ws[i] = W[i];
    for (int i = threadIdx.x; i < ROWS * FIN; i += 256) {
        int r = i / FIN, k = i - r * FIN;
        int gr = row0 + r;
        Xs[r][k] = (gr < n) ? X[(size_t)gr * FIN + k] : 0.0f;
    }
    __syncthreads();

    const int r  = threadIdx.x / NCG;
    const int cg = threadIdx.x % NCG;
    float4 acc = {0.f, 0.f, 0.f, 0.f};
    #pragma unroll 4
    for (int k = 0; k < FIN; ++k) {
        float xv = Xs[r][k];
        const float4 w4 = *reinterpret_cast<const float4*>(&Ws[k * FOUT + cg * 4]);
        acc.x += xv * w4.x; acc.y += xv * w4.y;
        acc.z += xv * w4.z; acc.w += xv * w4.w;
    }
    const int gr = row0 + r;
    if (gr < n) {
        float di = dinv[gr];
        acc.x *= di; acc.y *= di; acc.z *= di; acc.w *= di;
        *reinterpret_cast<float4*>(&G[(size_t)gr * FOUT + cg * 4]) = acc;
    }
}

// ---------------- SpMM gather + fused epilogue (layers 1,2) ----------------
template<int F, bool RELU>
__global__ void spmm(const int* __restrict__ rowptr, const int* __restrict__ csr_src,
                     const float* __restrict__ g, const float* __restrict__ dinv,
                     const float* __restrict__ b, float* __restrict__ out, int n) {
    int gi = blockIdx.x * blockDim.x + threadIdx.x;
    int node = gi / F;
    int lane = gi % F;
    if (node >= n) return;
    int beg = rowptr[node], end = rowptr[node + 1];
    float acc = 0.f;
    int j = beg;
    for (; j + 3 < end; j += 4) {          // 4 independent gathers in flight
        int s0 = csr_src[j], s1 = csr_src[j + 1], s2 = csr_src[j + 2], s3 = csr_src[j + 3];
        acc += g[(size_t)s0 * F + lane];
        acc += g[(size_t)s1 * F + lane];
        acc += g[(size_t)s2 * F + lane];
        acc += g[(size_t)s3 * F + lane];
    }
    for (; j < end; ++j) acc += g[(size_t)csr_src[j] * F + lane];
    float v = dinv[node] * (acc + g[(size_t)node * F + lane]) + b[lane];
    if (RELU) v = fmaxf(v, 0.f);
    out[(size_t)node * F + lane] = v;
}

// ---------------- layer 3: SpMM(F=16) + bias + log_softmax fused (16-lane shfl) ----------------
__global__ void spmm16_ls(const int* __restrict__ rowptr, const int* __restrict__ csr_src,
                          const float* __restrict__ g, const float* __restrict__ dinv,
                          const float* __restrict__ b, float* __restrict__ out, int n) {
    int gi = blockIdx.x * blockDim.x + threadIdx.x;
    int node = gi >> 4;
    int lane = gi & 15;
    if (node >= n) return;
    int beg = rowptr[node], end = rowptr[node + 1];
    float acc = 0.f;
    int j = beg;
    for (; j + 3 < end; j += 4) {
        int s0 = csr_src[j], s1 = csr_src[j + 1], s2 = csr_src[j + 2], s3 = csr_src[j + 3];
        acc += g[(size_t)s0 * 16 + lane];
        acc += g[(size_t)s1 * 16 + lane];
        acc += g[(size_t)s2 * 16 + lane];
        acc += g[(size_t)s3 * 16 + lane];
    }
    for (; j < end; ++j) acc += g[(size_t)csr_src[j] * 16 + lane];
    float v = dinv[node] * (acc + g[(size_t)node * 16 + lane]) + b[lane];
    // log-softmax across the 16 lanes of this node (quarter-wave shuffles)
    float m = v;
    #pragma unroll
    for (int o = 1; o < 16; o <<= 1) m = fmaxf(m, __shfl_xor(m, o, 64));
    float e = __expf(v - m);
    float ssum = e;
    #pragma unroll
    for (int o = 1; o < 16; o <<= 1) ssum += __shfl_xor(ssum, o, 64);
    out[(size_t)node * 16 + lane] = v - m - __logf(ssum);
}

extern "C" void kernel_launch(void* const* d_in, const int* in_sizes, int n_in,
                              void* d_out, int out_size, void* d_ws, size_t ws_size,
                              hipStream_t stream) {
    const float* x  = (const float*)d_in[0];
    const int*   ei = (const int*)d_in[1];
    const float* W1 = (const float*)d_in[2];
    const float* b1 = (const float*)d_in[3];
    const float* W2 = (const float*)d_in[4];
    const float* b2 = (const float*)d_in[5];
    const float* W3 = (const float*)d_in[6];
    const float* b3 = (const float*)d_in[7];
    float* out = (float*)d_out;

    const int n = in_sizes[0] / 256;     // 100000
    const int E = in_sizes[1] / 2;       // 3200000
    const int* src = ei;
    const int* dst = ei + E;

    const int NP = ((n + 256) + 255) / 256 * 256;   // padded node slots (>= n+1)
    const int NB = (n + BWIDTH - 1) >> BSHIFT;      // buckets (1563)

    // workspace layout (4-byte units)
    int*   cnt     = (int*)d_ws;               // NP
    int*   rowptr  = cnt + NP;                 // NP (uses n+1)
    int*   bsum    = rowptr + NP;              // 512
    float* dinv    = (float*)(bsum + 512);     // NP
    int*   bcnt    = (int*)(dinv + NP);        // MAXNB
    int*   bbase   = bcnt + MAXNB;             // MAXNB+16
    int*   bfill   = bbase + MAXNB + 16;       // MAXNB*16 (padded cursors)
    int*   csr_src = bfill + MAXNB * 16;       // E
    float* g1      = (float*)(csr_src + E);    // n*32
    float* a1      = g1 + (size_t)n * 32;      // n*32
    float* g2      = a1 + (size_t)n * 32;      // n*64
    float* a2      = g2 + (size_t)n * 64;      // n*64
    float* g3      = g1;                       // n*16 (reuse)
    int2*  ebuf    = (int2*)g1;                // E int2 (aliases g1..a1; dead before gemm1)

    const int T = 256;
    const int nb = (n + 255) / 256;

    // ---- CSR build + dinv (two-level counting sort) ----
    hipMemsetAsync(bcnt, 0, (size_t)MAXNB * 4, stream);
    p1_hist<<<256, T, 0, stream>>>(dst, E, bcnt, NB);
    p1_scan<<<1, 1024, 0, stream>>>(bcnt, NB, E, bbase, bfill);
    p1_scatter<<<(E + T - 1) / T, T, 0, stream>>>(src, dst, E, bfill, ebuf);
    p2_hist<<<NB, T, 0, stream>>>(ebuf, bbase, cnt, n);
    scan_block_sums<<<nb, 256, 0, stream>>>(cnt, n, bsum);
    scan_small<<<1, 512, 0, stream>>>(bsum, nb);
    scan_write<<<nb, 256, 0, stream>>>(cnt, n, bsum, rowptr, dinv);
    p2_scatter<<<NB, T, 0, stream>>>(ebuf, bbase, rowptr, csr_src, n);

    // ---- layer 1: 256 -> 32, relu ----
    gemm_small<256, 32, 32><<<(n + 31) / 32, T, 0, stream>>>(x, W1, dinv, g1, n);
    spmm<32, true><<<((size_t)n * 32 + T - 1) / T, T, 0, stream>>>(rowptr, csr_src, g1, dinv, b1, a1, n);

    // ---- layer 2: 32 -> 64, relu ----
    gemm_small<32, 64, 16><<<(n + 15) / 16, T, 0, stream>>>(a1, W2, dinv, g2, n);
    spmm<64, true><<<((size_t)n * 64 + T - 1) / T, T, 0, stream>>>(rowptr, csr_src, g2, dinv, b2, a2, n);

    // ---- layer 3: 64 -> 16, fused spmm + log_softmax ----
    gemm_small<64, 16, 64><<<(n + 63) / 64, T, 0, stream>>>(a2, W3, dinv, g3, n);
    spmm16_ls<<<((size_t)n * 16 + T - 1) / T, T, 0, stream>>>(rowptr, csr_src, g3, dinv, b3, out, n);
}

// Round 5
// 630.780 us; speedup vs baseline: 7.9311x; 1.3722x over previous
//
#include <hip/hip_runtime.h>
#include <hip/hip_bf16.h>

// 3-layer GCN, CSR-gather formulation.
// CSR build = deterministic two-level counting sort (no contended global atomics):
//   pass 1: tile-local multi-split into 391 coarse buckets (256 nodes each) via a
//           2-D histogram [bucket][tile] + exclusive scan -> exact write positions,
//           LDS-staged scatter with coalesced run writes (packed (src<<8)|local).
//   pass 2: per-bucket 256-bin LDS histogram (+dinv) -> node scan -> LDS-cursor
//           scatter into bucket-local csr ranges (single-writer, L2-resident).

#define TILE 2048
#define EPT  8          // edges per thread = TILE/256
#define MAXB 512        // max coarse buckets (n <= 131072)

// ---------------- pass 1a: per-tile bucket histogram, coalesced [t][b] layout ----------------
__global__ __launch_bounds__(256) void hist2d_kernel(const int* __restrict__ dst, int E,
                                                     int NB1, int* __restrict__ histT) {
    __shared__ int h[MAXB];
    int t = blockIdx.x;
    for (int i = threadIdx.x; i < MAXB; i += 256) h[i] = 0;
    __syncthreads();
    int base = t * TILE;
    #pragma unroll
    for (int i = 0; i < EPT; ++i) {
        int e = base + threadIdx.x + i * 256;
        if (e < E) atomicAdd(&h[dst[e] >> 8], 1);
    }
    __syncthreads();
    for (int i = threadIdx.x; i < NB1; i += 256)
        histT[(size_t)t * NB1 + i] = h[i];
}

// ---------------- tiled transpose: histT[t][b] -> hist[b][t] ----------------
__global__ void transpose32(const int* __restrict__ in, int rows, int cols,
                            int* __restrict__ out) {
    __shared__ int tile[32][33];
    int c = blockIdx.x * 32 + threadIdx.x;
    int r = blockIdx.y * 32 + threadIdx.y;
    if (r < rows && c < cols) tile[threadIdx.y][threadIdx.x] = in[(size_t)r * cols + c];
    __syncthreads();
    int tr = blockIdx.x * 32 + threadIdx.y;   // output row (cols-dim)
    int tc = blockIdx.y * 32 + threadIdx.x;   // output col (rows-dim)
    if (tr < cols && tc < rows) out[(size_t)tr * rows + tc] = tile[threadIdx.x][threadIdx.y];
}

// ---------------- generic exclusive scan (3 kernels) ----------------
__global__ void scan_bsum(const int* __restrict__ in, int n, int* __restrict__ bsum) {
    __shared__ int s[256];
    int i = blockIdx.x * 256 + threadIdx.x;
    s[threadIdx.x] = (i < n) ? in[i] : 0;
    __syncthreads();
    for (int o = 128; o > 0; o >>= 1) {
        if (threadIdx.x < o) s[threadIdx.x] += s[threadIdx.x + o];
        __syncthreads();
    }
    if (threadIdx.x == 0) bsum[blockIdx.x] = s[0];
}

__global__ void scan_carry(int* __restrict__ bsum, int nb) {   // 1 block, 1024 thr, chunked
    __shared__ int s[1024];
    __shared__ int carry;
    if (threadIdx.x == 0) carry = 0;
    __syncthreads();
    for (int base = 0; base < nb; base += 1024) {
        int idx = base + threadIdx.x;
        int v = (idx < nb) ? bsum[idx] : 0;
        s[threadIdx.x] = v;
        __syncthreads();
        for (int o = 1; o < 1024; o <<= 1) {
            int t = (threadIdx.x >= o) ? s[threadIdx.x - o] : 0;
            __syncthreads();
            s[threadIdx.x] += t;
            __syncthreads();
        }
        if (idx < nb) bsum[idx] = carry + s[threadIdx.x] - v;   // exclusive
        __syncthreads();
        if (threadIdx.x == 0) carry += s[1023];
        __syncthreads();
    }
}

__global__ void scan_emit(const int* __restrict__ in, int n, const int* __restrict__ bsum,
                          int* __restrict__ out, int total) {
    __shared__ int s[256];
    int i = blockIdx.x * 256 + threadIdx.x;
    int v = (i < n) ? in[i] : 0;
    s[threadIdx.x] = v;
    __syncthreads();
    for (int o = 1; o < 256; o <<= 1) {
        int t = (threadIdx.x >= o) ? s[threadIdx.x - o] : 0;
        __syncthreads();
        s[threadIdx.x] += t;
        __syncthreads();
    }
    if (i < n) {
        int excl = bsum[blockIdx.x] + s[threadIdx.x] - v;
        out[i] = excl;
        if (total && i == n - 1) out[n] = excl + v;
    }
}

// ---------------- pass 1b: deterministic LDS-staged multi-split scatter ----------------
__global__ __launch_bounds__(256) void p1_scatter_tiled(const int* __restrict__ src,
                                                        const int* __restrict__ dst, int E,
                                                        int NB1, int NT,
                                                        const int* __restrict__ scanned,
                                                        int* __restrict__ ebuf) {
    __shared__ int h[MAXB], hb[MAXB], cur[MAXB], gb[MAXB];
    __shared__ int s2[256];
    __shared__ int stash[TILE];
    __shared__ unsigned short sb[TILE];
    const int t = blockIdx.x;
    for (int i = threadIdx.x; i < MAXB; i += 256) h[i] = 0;
    for (int i = threadIdx.x; i < NB1; i += 256)
        gb[i] = scanned[(size_t)i * NT + t];
    __syncthreads();
    const int base = t * TILE;
    int pk[EPT], cb[EPT];
    #pragma unroll
    for (int i = 0; i < EPT; ++i) {
        int e = base + threadIdx.x + i * 256;
        if (e < E) {
            int s = src[e], d = dst[e];
            pk[i] = (s << 8) | (d & 255);
            cb[i] = d >> 8;
            atomicAdd(&h[cb[i]], 1);
        } else cb[i] = -1;
    }
    __syncthreads();
    // exclusive scan of h[0..MAXB) with 256 threads (pair + Hillis-Steele)
    int a = h[2 * threadIdx.x], b2 = h[2 * threadIdx.x + 1];
    s2[threadIdx.x] = a + b2;
    __syncthreads();
    for (int o = 1; o < 256; o <<= 1) {
        int tv = (threadIdx.x >= o) ? s2[threadIdx.x - o] : 0;
        __syncthreads();
        s2[threadIdx.x] += tv;
        __syncthreads();
    }
    int excl2 = s2[threadIdx.x] - (a + b2);
    hb[2 * threadIdx.x]     = excl2;
    hb[2 * threadIdx.x + 1] = excl2 + a;
    cur[2 * threadIdx.x]     = excl2;
    cur[2 * threadIdx.x + 1] = excl2 + a;
    __syncthreads();
    // scatter tile into LDS, ordered by bucket
    #pragma unroll
    for (int i = 0; i < EPT; ++i) if (cb[i] >= 0) {
        int p = atomicAdd(&cur[cb[i]], 1);
        stash[p] = pk[i];
        sb[p] = (unsigned short)cb[i];
    }
    __syncthreads();
    // write out: per-bucket runs are contiguous in LDS and in global -> coalesced
    const int cnt_t = min(TILE, E - base);
    for (int j = threadIdx.x; j < cnt_t; j += 256) {
        int b = sb[j];
        ebuf[gb[b] + (j - hb[b])] = stash[j];
    }
}

// ---------------- pass 2a: per-bucket node histogram + dinv ----------------
__global__ __launch_bounds__(256) void p2_hist(const int* __restrict__ ebuf,
                                               const int* __restrict__ scanned, int NT, int NB1,
                                               int E, int* __restrict__ cnt,
                                               float* __restrict__ dinv, int n) {
    int b = blockIdx.x;
    __shared__ int h[256];
    h[threadIdx.x] = 0;
    __syncthreads();
    int beg = scanned[(size_t)b * NT];
    int end = (b + 1 < NB1) ? scanned[(size_t)(b + 1) * NT] : E;
    for (int i = beg + threadIdx.x; i < end; i += 256)
        atomicAdd(&h[ebuf[i] & 255], 1);
    __syncthreads();
    int node = b * 256 + threadIdx.x;
    if (node < n) {
        int v = h[threadIdx.x];
        cnt[node] = v;
        float x = 1.0f + (float)v;
        float r = rsqrtf(x);
        r = r * (1.5f - 0.5f * x * r * r);   // Newton refine to full f32 precision
        dinv[node] = r;
    }
}

// ---------------- pass 2b: LDS-cursor scatter into csr (bucket-local, single writer) ----------------
__global__ __launch_bounds__(256) void p2_scatter(const int* __restrict__ ebuf,
                                                  const int* __restrict__ scanned, int NT, int NB1,
                                                  int E, const int* __restrict__ rowptr,
                                                  int* __restrict__ csr_src, int n) {
    int b = blockIdx.x;
    __shared__ int cur[256];
    int node = b * 256 + threadIdx.x;
    cur[threadIdx.x] = (node < n) ? rowptr[node] : 0;
    __syncthreads();
    int beg = scanned[(size_t)b * NT];
    int end = (b + 1 < NB1) ? scanned[(size_t)(b + 1) * NT] : E;
    for (int i = beg + threadIdx.x; i < end; i += 256) {
        int v = ebuf[i];
        int p = atomicAdd(&cur[v & 255], 1);
        csr_src[p] = v >> 8;
    }
}

// ---------------- small GEMM: G[n,FOUT] = (X[n,FIN] @ W[FIN,FOUT]) * dinv[row] ----------------
template<int FIN, int FOUT, int ROWS>
__global__ __launch_bounds__(256) void gemm_small(const float* __restrict__ X,
                                                  const float* __restrict__ W,
                                                  const float* __restrict__ dinv,
                                                  float* __restrict__ G, int n) {
    constexpr int NCG = FOUT / 4;            // col groups of 4; ROWS = 256/NCG
    __shared__ float Ws[FIN * FOUT];
    __shared__ float Xs[ROWS][FIN + 1];
    const int row0 = blockIdx.x * ROWS;

    for (int i = threadIdx.x; i < FIN * FOUT; i += 256) Ws[i] = W[i];
    for (int i = threadIdx.x; i < ROWS * FIN; i += 256) {
        int r = i / FIN, k = i - r * FIN;
        int gr = row0 + r;
        Xs[r][k] = (gr < n) ? X[(size_t)gr * FIN + k] : 0.0f;
    }
    __syncthreads();

    const int r  = threadIdx.x / NCG;
    const int cg = threadIdx.x % NCG;
    float4 acc = {0.f, 0.f, 0.f, 0.f};
    #pragma unroll 4
    for (int k = 0; k < FIN; ++k) {
        float xv = Xs[r][k];
        const float4 w4 = *reinterpret_cast<const float4*>(&Ws[k * FOUT + cg * 4]);
        acc.x += xv * w4.x; acc.y += xv * w4.y;
        acc.z += xv * w4.z; acc.w += xv * w4.w;
    }
    const int gr = row0 + r;
    if (gr < n) {
        float di = dinv[gr];
        acc.x *= di; acc.y *= di; acc.z *= di; acc.w *= di;
        *reinterpret_cast<float4*>(&G[(size_t)gr * FOUT + cg * 4]) = acc;
    }
}

// ---------------- SpMM gather + fused epilogue (layers 1,2) ----------------
template<int F, bool RELU>
__global__ void spmm(const int* __restrict__ rowptr, const int* __restrict__ csr_src,
                     const float* __restrict__ g, const float* __restrict__ dinv,
                     const float* __restrict__ b, float* __restrict__ out, int n) {
    int gi = blockIdx.x * blockDim.x + threadIdx.x;
    int node = gi / F;
    int lane = gi % F;
    if (node >= n) return;
    int beg = rowptr[node], end = rowptr[node + 1];
    float acc = 0.f;
    int j = beg;
    for (; j + 3 < end; j += 4) {
        int s0 = csr_src[j], s1 = csr_src[j + 1], s2 = csr_src[j + 2], s3 = csr_src[j + 3];
        acc += g[(size_t)s0 * F + lane];
        acc += g[(size_t)s1 * F + lane];
        acc += g[(size_t)s2 * F + lane];
        acc += g[(size_t)s3 * F + lane];
    }
    for (; j < end; ++j) acc += g[(size_t)csr_src[j] * F + lane];
    float v = dinv[node] * (acc + g[(size_t)node * F + lane]) + b[lane];
    if (RELU) v = fmaxf(v, 0.f);
    out[(size_t)node * F + lane] = v;
}

// ---------------- layer 3: SpMM(F=16) + bias + log_softmax fused ----------------
__global__ void spmm16_ls(const int* __restrict__ rowptr, const int* __restrict__ csr_src,
                          const float* __restrict__ g, const float* __restrict__ dinv,
                          const float* __restrict__ b, float* __restrict__ out, int n) {
    int gi = blockIdx.x * blockDim.x + threadIdx.x;
    int node = gi >> 4;
    int lane = gi & 15;
    if (node >= n) return;
    int beg = rowptr[node], end = rowptr[node + 1];
    float acc = 0.f;
    int j = beg;
    for (; j + 3 < end; j += 4) {
        int s0 = csr_src[j], s1 = csr_src[j + 1], s2 = csr_src[j + 2], s3 = csr_src[j + 3];
        acc += g[(size_t)s0 * 16 + lane];
        acc += g[(size_t)s1 * 16 + lane];
        acc += g[(size_t)s2 * 16 + lane];
        acc += g[(size_t)s3 * 16 + lane];
    }
    for (; j < end; ++j) acc += g[(size_t)csr_src[j] * 16 + lane];
    float v = dinv[node] * (acc + g[(size_t)node * 16 + lane]) + b[lane];
    float m = v;
    #pragma unroll
    for (int o = 1; o < 16; o <<= 1) m = fmaxf(m, __shfl_xor(m, o, 64));
    float e = __expf(v - m);
    float ssum = e;
    #pragma unroll
    for (int o = 1; o < 16; o <<= 1) ssum += __shfl_xor(ssum, o, 64);
    out[(size_t)node * 16 + lane] = v - m - __logf(ssum);
}

extern "C" void kernel_launch(void* const* d_in, const int* in_sizes, int n_in,
                              void* d_out, int out_size, void* d_ws, size_t ws_size,
                              hipStream_t stream) {
    const float* x  = (const float*)d_in[0];
    const int*   ei = (const int*)d_in[1];
    const float* W1 = (const float*)d_in[2];
    const float* b1 = (const float*)d_in[3];
    const float* W2 = (const float*)d_in[4];
    const float* b2 = (const float*)d_in[5];
    const float* W3 = (const float*)d_in[6];
    const float* b3 = (const float*)d_in[7];
    float* out = (float*)d_out;

    const int n = in_sizes[0] / 256;     // 100000
    const int E = in_sizes[1] / 2;       // 3200000
    const int* src = ei;
    const int* dst = ei + E;

    const int NP  = ((n + 256) + 255) / 256 * 256;   // padded node slots (>= n+1)
    const int NB1 = (n + 255) / 256;                 // coarse buckets (391)
    const int NT  = (E + TILE - 1) / TILE;           // tiles (1563)
    const int M   = NB1 * NT;                        // 2-D hist size (~611K)

    // workspace layout (4-byte units)
    int*   cnt     = (int*)d_ws;               // NP
    int*   rowptr  = cnt + NP;                 // NP (n+1 used)
    int*   bsum    = rowptr + NP;              // 512
    int*   bsum2   = bsum + 512;               // 4096
    float* dinv    = (float*)(bsum2 + 4096);   // NP
    int*   csr_src = (int*)(dinv + NP);        // E
    float* g1      = (float*)(csr_src + E);    // n*32
    float* a1      = g1 + (size_t)n * 32;      // n*32
    float* g2      = a1 + (size_t)n * 32;      // n*64
    float* a2      = g2 + (size_t)n * 64;      // n*64
    float* g3      = g1;                       // n*16 (reuse)
    int*   ebuf    = (int*)g1;                 // E ints (== g1 size; dead before gemm1)
    int*   histT   = (int*)g2;                 // M ints (dead before gemm2)
    int*   hist2d  = histT + ((M + 255) & ~255);   // M ints
    int*   scanned = (int*)a2;                 // M ints (dead before spmm<64>)

    const int T = 256;
    const int nb  = (n + 255) / 256;
    const int MB  = (M + 255) / 256;

    // ---- pass 1: 2-D histogram -> transpose -> scan -> deterministic scatter ----
    hist2d_kernel<<<NT, T, 0, stream>>>(dst, E, NB1, histT);
    transpose32<<<dim3((NB1 + 31) / 32, (NT + 31) / 32), dim3(32, 32), 0, stream>>>(
        histT, NT, NB1, hist2d);
    scan_bsum<<<MB, T, 0, stream>>>(hist2d, M, bsum2);
    scan_carry<<<1, 1024, 0, stream>>>(bsum2, MB);
    scan_emit<<<MB, T, 0, stream>>>(hist2d, M, bsum2, scanned, 0);
    p1_scatter_tiled<<<NT, T, 0, stream>>>(src, dst, E, NB1, NT, scanned, ebuf);

    // ---- pass 2: per-bucket hist (+dinv) -> node scan -> csr scatter ----
    p2_hist<<<NB1, T, 0, stream>>>(ebuf, scanned, NT, NB1, E, cnt, dinv, n);
    scan_bsum<<<nb, T, 0, stream>>>(cnt, n, bsum);
    scan_carry<<<1, 1024, 0, stream>>>(bsum, nb);
    scan_emit<<<nb, T, 0, stream>>>(cnt, n, bsum, rowptr, 1);
    p2_scatter<<<NB1, T, 0, stream>>>(ebuf, scanned, NT, NB1, E, rowptr, csr_src, n);

    // ---- layer 1: 256 -> 32, relu ----
    gemm_small<256, 32, 32><<<(n + 31) / 32, T, 0, stream>>>(x, W1, dinv, g1, n);
    spmm<32, true><<<((size_t)n * 32 + T - 1) / T, T, 0, stream>>>(rowptr, csr_src, g1, dinv, b1, a1, n);

    // ---- layer 2: 32 -> 64, relu ----
    gemm_small<32, 64, 16><<<(n + 15) / 16, T, 0, stream>>>(a1, W2, dinv, g2, n);
    spmm<64, true><<<((size_t)n * 64 + T - 1) / T, T, 0, stream>>>(rowptr, csr_src, g2, dinv, b2, a2, n);

    // ---- layer 3: 64 -> 16, fused spmm + log_softmax ----
    gemm_small<64, 16, 64><<<(n + 63) / 64, T, 0, stream>>>(a2, W3, dinv, g3, n);
    spmm16_ls<<<((size_t)n * 16 + T - 1) / T, T, 0, stream>>>(rowptr, csr_src, g3, dinv, b3, out, n);
}

// Round 8
// 530.970 us; speedup vs baseline: 9.4219x; 1.1880x over previous
//
#include <hip/hip_runtime.h>
#include <hip/hip_bf16.h>

// 3-layer GCN, CSR-gather formulation.
// CSR build = deterministic two-level counting sort (no contended global atomics).
// GEMMs = register-blocked 4x4 tiles, K-chunked, transposed-X LDS staging.

#define TILE 2048
#define EPT  8          // edges per thread = TILE/256
#define MAXB 512        // max coarse buckets (n <= 131072)

// ---------------- pass 1a: per-tile bucket histogram, coalesced [t][b] layout ----------------
__global__ __launch_bounds__(256) void hist2d_kernel(const int* __restrict__ dst, int E,
                                                     int NB1, int* __restrict__ histT) {
    __shared__ int h[MAXB];
    int t = blockIdx.x;
    for (int i = threadIdx.x; i < MAXB; i += 256) h[i] = 0;
    __syncthreads();
    int base = t * TILE;
    #pragma unroll
    for (int i = 0; i < EPT; ++i) {
        int e = base + threadIdx.x + i * 256;
        if (e < E) atomicAdd(&h[dst[e] >> 8], 1);
    }
    __syncthreads();
    for (int i = threadIdx.x; i < NB1; i += 256)
        histT[(size_t)t * NB1 + i] = h[i];
}

// ---------------- tiled transpose: histT[t][b] -> hist[b][t] ----------------
__global__ void transpose32(const int* __restrict__ in, int rows, int cols,
                            int* __restrict__ out) {
    __shared__ int tile[32][33];
    int c = blockIdx.x * 32 + threadIdx.x;
    int r = blockIdx.y * 32 + threadIdx.y;
    if (r < rows && c < cols) tile[threadIdx.y][threadIdx.x] = in[(size_t)r * cols + c];
    __syncthreads();
    int tr = blockIdx.x * 32 + threadIdx.y;   // output row (cols-dim)
    int tc = blockIdx.y * 32 + threadIdx.x;   // output col (rows-dim)
    if (tr < cols && tc < rows) out[(size_t)tr * rows + tc] = tile[threadIdx.x][threadIdx.y];
}

// ---------------- generic exclusive scan (3 kernels) ----------------
__global__ void scan_bsum(const int* __restrict__ in, int n, int* __restrict__ bsum) {
    __shared__ int s[256];
    int i = blockIdx.x * 256 + threadIdx.x;
    s[threadIdx.x] = (i < n) ? in[i] : 0;
    __syncthreads();
    for (int o = 128; o > 0; o >>= 1) {
        if (threadIdx.x < o) s[threadIdx.x] += s[threadIdx.x + o];
        __syncthreads();
    }
    if (threadIdx.x == 0) bsum[blockIdx.x] = s[0];
}

__global__ void scan_carry(int* __restrict__ bsum, int nb) {   // 1 block, 1024 thr, chunked
    __shared__ int s[1024];
    __shared__ int carry;
    if (threadIdx.x == 0) carry = 0;
    __syncthreads();
    for (int base = 0; base < nb; base += 1024) {
        int idx = base + threadIdx.x;
        int v = (idx < nb) ? bsum[idx] : 0;
        s[threadIdx.x] = v;
        __syncthreads();
        for (int o = 1; o < 1024; o <<= 1) {
            int t = (threadIdx.x >= o) ? s[threadIdx.x - o] : 0;
            __syncthreads();
            s[threadIdx.x] += t;
            __syncthreads();
        }
        if (idx < nb) bsum[idx] = carry + s[threadIdx.x] - v;   // exclusive
        __syncthreads();
        if (threadIdx.x == 0) carry += s[1023];
        __syncthreads();
    }
}

__global__ void scan_emit(const int* __restrict__ in, int n, const int* __restrict__ bsum,
                          int* __restrict__ out, int total) {
    __shared__ int s[256];
    int i = blockIdx.x * 256 + threadIdx.x;
    int v = (i < n) ? in[i] : 0;
    s[threadIdx.x] = v;
    __syncthreads();
    for (int o = 1; o < 256; o <<= 1) {
        int t = (threadIdx.x >= o) ? s[threadIdx.x - o] : 0;
        __syncthreads();
        s[threadIdx.x] += t;
        __syncthreads();
    }
    if (i < n) {
        int excl = bsum[blockIdx.x] + s[threadIdx.x] - v;
        out[i] = excl;
        if (total && i == n - 1) out[n] = excl + v;
    }
}

// ---------------- pass 1b: deterministic LDS-staged multi-split scatter ----------------
__global__ __launch_bounds__(256) void p1_scatter_tiled(const int* __restrict__ src,
                                                        const int* __restrict__ dst, int E,
                                                        int NB1, int NT,
                                                        const int* __restrict__ scanned,
                                                        int* __restrict__ ebuf) {
    __shared__ int h[MAXB], hb[MAXB], cur[MAXB], gb[MAXB];
    __shared__ int s2[256];
    __shared__ int stash[TILE];
    __shared__ unsigned short sb[TILE];
    const int t = blockIdx.x;
    for (int i = threadIdx.x; i < MAXB; i += 256) h[i] = 0;
    for (int i = threadIdx.x; i < NB1; i += 256)
        gb[i] = scanned[(size_t)i * NT + t];
    __syncthreads();
    const int base = t * TILE;
    int pk[EPT], cb[EPT];
    #pragma unroll
    for (int i = 0; i < EPT; ++i) {
        int e = base + threadIdx.x + i * 256;
        if (e < E) {
            int s = src[e], d = dst[e];
            pk[i] = (s << 8) | (d & 255);
            cb[i] = d >> 8;
            atomicAdd(&h[cb[i]], 1);
        } else cb[i] = -1;
    }
    __syncthreads();
    // exclusive scan of h[0..MAXB) with 256 threads (pair + Hillis-Steele)
    int a = h[2 * threadIdx.x], b2 = h[2 * threadIdx.x + 1];
    s2[threadIdx.x] = a + b2;
    __syncthreads();
    for (int o = 1; o < 256; o <<= 1) {
        int tv = (threadIdx.x >= o) ? s2[threadIdx.x - o] : 0;
        __syncthreads();
        s2[threadIdx.x] += tv;
        __syncthreads();
    }
    int excl2 = s2[threadIdx.x] - (a + b2);
    hb[2 * threadIdx.x]     = excl2;
    hb[2 * threadIdx.x + 1] = excl2 + a;
    cur[2 * threadIdx.x]     = excl2;
    cur[2 * threadIdx.x + 1] = excl2 + a;
    __syncthreads();
    // scatter tile into LDS, ordered by bucket
    #pragma unroll
    for (int i = 0; i < EPT; ++i) if (cb[i] >= 0) {
        int p = atomicAdd(&cur[cb[i]], 1);
        stash[p] = pk[i];
        sb[p] = (unsigned short)cb[i];
    }
    __syncthreads();
    // write out: per-bucket runs are contiguous in LDS and in global -> coalesced
    const int cnt_t = min(TILE, E - base);
    for (int j = threadIdx.x; j < cnt_t; j += 256) {
        int b = sb[j];
        ebuf[gb[b] + (j - hb[b])] = stash[j];
    }
}

// ---------------- pass 2a: per-bucket node histogram + dinv ----------------
__global__ __launch_bounds__(256) void p2_hist(const int* __restrict__ ebuf,
                                               const int* __restrict__ scanned, int NT, int NB1,
                                               int E, int* __restrict__ cnt,
                                               float* __restrict__ dinv, int n) {
    int b = blockIdx.x;
    __shared__ int h[256];
    h[threadIdx.x] = 0;
    __syncthreads();
    int beg = scanned[(size_t)b * NT];
    int end = (b + 1 < NB1) ? scanned[(size_t)(b + 1) * NT] : E;
    for (int i = beg + threadIdx.x; i < end; i += 256)
        atomicAdd(&h[ebuf[i] & 255], 1);
    __syncthreads();
    int node = b * 256 + threadIdx.x;
    if (node < n) {
        int v = h[threadIdx.x];
        cnt[node] = v;
        float x = 1.0f + (float)v;
        float r = rsqrtf(x);
        r = r * (1.5f - 0.5f * x * r * r);   // Newton refine to full f32 precision
        dinv[node] = r;
    }
}

// ---------------- pass 2b: LDS-cursor scatter into csr (bucket-local, single writer) ----------------
__global__ __launch_bounds__(256) void p2_scatter(const int* __restrict__ ebuf,
                                                  const int* __restrict__ scanned, int NT, int NB1,
                                                  int E, const int* __restrict__ rowptr,
                                                  int* __restrict__ csr_src, int n) {
    int b = blockIdx.x;
    __shared__ int cur[256];
    int node = b * 256 + threadIdx.x;
    cur[threadIdx.x] = (node < n) ? rowptr[node] : 0;
    __syncthreads();
    int beg = scanned[(size_t)b * NT];
    int end = (b + 1 < NB1) ? scanned[(size_t)(b + 1) * NT] : E;
    for (int i = beg + threadIdx.x; i < end; i += 256) {
        int v = ebuf[i];
        int p = atomicAdd(&cur[v & 255], 1);
        csr_src[p] = v >> 8;
    }
}

// ---------------- register-blocked GEMM: G = (X[n,FIN] @ W[FIN,FOUT]) * dinv[row] ----------------
// 256 threads; each thread owns a 4x4 output tile (4 rows x 4 cols).
// K chunked by 32; X staged TRANSPOSED (Xt[k][row], row-len R+4 -> aligned b128,
// conflict-free inner reads). Inner loop per k: 2x ds_read_b128 feeding 16 FMAs.
template<int FIN, int FOUT>
__global__ __launch_bounds__(256) void gemm_reg(const float* __restrict__ X,
                                                const float* __restrict__ W,
                                                const float* __restrict__ dinv,
                                                float* __restrict__ G, int n) {
    constexpr int KC  = 32;
    constexpr int NCG = FOUT / 4;        // col-groups of 4
    constexpr int NRG = 256 / NCG;       // row-groups
    constexpr int R   = NRG * 4;         // rows per block
    constexpr int RL  = R + 4;           // Xt row length: %4==0 (b128-aligned), breaks pow2 stride
    __shared__ float Xt[KC][RL];
    __shared__ float Ws[KC][FOUT];

    const int row0 = blockIdx.x * R;
    const int cg = threadIdx.x % NCG;
    const int rg = threadIdx.x / NCG;
    const int r0 = rg * 4;

    float acc[4][4];
    #pragma unroll
    for (int i = 0; i < 4; ++i)
        #pragma unroll
        for (int j = 0; j < 4; ++j) acc[i][j] = 0.f;

    for (int kc = 0; kc < FIN; kc += KC) {
        // stage W chunk (KC x FOUT, contiguous in W) -- coalesced float4
        constexpr int WF4 = KC * FOUT / 4;
        for (int i = threadIdx.x; i < WF4; i += 256)
            reinterpret_cast<float4*>(&Ws[0][0])[i] =
                reinterpret_cast<const float4*>(W + (size_t)kc * FOUT)[i];
        // stage X chunk transposed: R rows x KC cols
        constexpr int XF4 = R * KC / 4;
        for (int i = threadIdx.x; i < XF4; i += 256) {
            int row = i / (KC / 4);
            int kq  = i % (KC / 4);
            int grow = row0 + row;
            float4 v = (grow < n)
                ? *reinterpret_cast<const float4*>(X + (size_t)grow * FIN + kc + kq * 4)
                : make_float4(0.f, 0.f, 0.f, 0.f);
            Xt[kq * 4 + 0][row] = v.x;
            Xt[kq * 4 + 1][row] = v.y;
            Xt[kq * 4 + 2][row] = v.z;
            Xt[kq * 4 + 3][row] = v.w;
        }
        __syncthreads();
        #pragma unroll
        for (int k = 0; k < KC; ++k) {
            const float4 xv = *reinterpret_cast<const float4*>(&Xt[k][r0]);
            const float4 wv = *reinterpret_cast<const float4*>(&Ws[k][cg * 4]);
            const float xr[4] = {xv.x, xv.y, xv.z, xv.w};
            const float wr[4] = {wv.x, wv.y, wv.z, wv.w};
            #pragma unroll
            for (int i = 0; i < 4; ++i)
                #pragma unroll
                for (int j = 0; j < 4; ++j)
                    acc[i][j] += xr[i] * wr[j];
        }
        __syncthreads();
    }
    #pragma unroll
    for (int i = 0; i < 4; ++i) {
        int grow = row0 + r0 + i;
        if (grow < n) {
            float di = dinv[grow];
            float4 o = make_float4(acc[i][0] * di, acc[i][1] * di,
                                   acc[i][2] * di, acc[i][3] * di);
            *reinterpret_cast<float4*>(G + (size_t)grow * FOUT + cg * 4) = o;
        }
    }
}

// ---------------- SpMM gather + fused epilogue (layers 1,2) ----------------
template<int F, bool RELU>
__global__ void spmm(const int* __restrict__ rowptr, const int* __restrict__ csr_src,
                     const float* __restrict__ g, const float* __restrict__ dinv,
                     const float* __restrict__ b, float* __restrict__ out, int n) {
    int gi = blockIdx.x * blockDim.x + threadIdx.x;
    int node = gi / F;
    int lane = gi % F;
    if (node >= n) return;
    int beg = rowptr[node], end = rowptr[node + 1];
    float acc = 0.f;
    int j = beg;
    for (; j + 3 < end; j += 4) {
        int s0 = csr_src[j], s1 = csr_src[j + 1], s2 = csr_src[j + 2], s3 = csr_src[j + 3];
        acc += g[(size_t)s0 * F + lane];
        acc += g[(size_t)s1 * F + lane];
        acc += g[(size_t)s2 * F + lane];
        acc += g[(size_t)s3 * F + lane];
    }
    for (; j < end; ++j) acc += g[(size_t)csr_src[j] * F + lane];
    float v = dinv[node] * (acc + g[(size_t)node * F + lane]) + b[lane];
    if (RELU) v = fmaxf(v, 0.f);
    out[(size_t)node * F + lane] = v;
}

// ---------------- layer 3: SpMM(F=16) + bias + log_softmax fused ----------------
__global__ void spmm16_ls(const int* __restrict__ rowptr, const int* __restrict__ csr_src,
                          const float* __restrict__ g, const float* __restrict__ dinv,
                          const float* __restrict__ b, float* __restrict__ out, int n) {
    int gi = blockIdx.x * blockDim.x + threadIdx.x;
    int node = gi >> 4;
    int lane = gi & 15;
    if (node >= n) return;
    int beg = rowptr[node], end = rowptr[node + 1];
    float acc = 0.f;
    int j = beg;
    for (; j + 3 < end; j += 4) {
        int s0 = csr_src[j], s1 = csr_src[j + 1], s2 = csr_src[j + 2], s3 = csr_src[j + 3];
        acc += g[(size_t)s0 * 16 + lane];
        acc += g[(size_t)s1 * 16 + lane];
        acc += g[(size_t)s2 * 16 + lane];
        acc += g[(size_t)s3 * 16 + lane];
    }
    for (; j < end; ++j) acc += g[(size_t)csr_src[j] * 16 + lane];
    float v = dinv[node] * (acc + g[(size_t)node * 16 + lane]) + b[lane];
    float m = v;
    #pragma unroll
    for (int o = 1; o < 16; o <<= 1) m = fmaxf(m, __shfl_xor(m, o, 64));
    float e = __expf(v - m);
    float ssum = e;
    #pragma unroll
    for (int o = 1; o < 16; o <<= 1) ssum += __shfl_xor(ssum, o, 64);
    out[(size_t)node * 16 + lane] = v - m - __logf(ssum);
}

extern "C" void kernel_launch(void* const* d_in, const int* in_sizes, int n_in,
                              void* d_out, int out_size, void* d_ws, size_t ws_size,
                              hipStream_t stream) {
    const float* x  = (const float*)d_in[0];
    const int*   ei = (const int*)d_in[1];
    const float* W1 = (const float*)d_in[2];
    const float* b1 = (const float*)d_in[3];
    const float* W2 = (const float*)d_in[4];
    const float* b2 = (const float*)d_in[5];
    const float* W3 = (const float*)d_in[6];
    const float* b3 = (const float*)d_in[7];
    float* out = (float*)d_out;

    const int n = in_sizes[0] / 256;     // 100000
    const int E = in_sizes[1] / 2;       // 3200000
    const int* src = ei;
    const int* dst = ei + E;

    const int NP  = ((n + 256) + 255) / 256 * 256;   // padded node slots (>= n+1)
    const int NB1 = (n + 255) / 256;                 // coarse buckets (391)
    const int NT  = (E + TILE - 1) / TILE;           // tiles (1563)
    const int M   = NB1 * NT;                        // 2-D hist size (~611K)

    // workspace layout (4-byte units)
    int*   cnt     = (int*)d_ws;               // NP
    int*   rowptr  = cnt + NP;                 // NP (n+1 used)
    int*   bsum    = rowptr + NP;              // 512
    int*   bsum2   = bsum + 512;               // 4096
    float* dinv    = (float*)(bsum2 + 4096);   // NP
    int*   csr_src = (int*)(dinv + NP);        // E
    float* g1      = (float*)(csr_src + E);    // n*32
    float* a1      = g1 + (size_t)n * 32;      // n*32
    float* g2      = a1 + (size_t)n * 32;      // n*64
    float* a2      = g2 + (size_t)n * 64;      // n*64
    float* g3      = g1;                       // n*16 (reuse)
    int*   ebuf    = (int*)g1;                 // E ints (== g1 size; dead before gemm1)
    int*   histT   = (int*)g2;                 // M ints (dead before gemm2)
    int*   hist2d  = histT + ((M + 255) & ~255);   // M ints
    int*   scanned = (int*)a2;                 // M ints (dead before spmm<64>)

    const int T = 256;
    const int nb  = (n + 255) / 256;
    const int MB  = (M + 255) / 256;

    // ---- pass 1: 2-D histogram -> transpose -> scan -> deterministic scatter ----
    hist2d_kernel<<<NT, T, 0, stream>>>(dst, E, NB1, histT);
    transpose32<<<dim3((NB1 + 31) / 32, (NT + 31) / 32), dim3(32, 32), 0, stream>>>(
        histT, NT, NB1, hist2d);
    scan_bsum<<<MB, T, 0, stream>>>(hist2d, M, bsum2);
    scan_carry<<<1, 1024, 0, stream>>>(bsum2, MB);
    scan_emit<<<MB, T, 0, stream>>>(hist2d, M, bsum2, scanned, 0);
    p1_scatter_tiled<<<NT, T, 0, stream>>>(src, dst, E, NB1, NT, scanned, ebuf);

    // ---- pass 2: per-bucket hist (+dinv) -> node scan -> csr scatter ----
    p2_hist<<<NB1, T, 0, stream>>>(ebuf, scanned, NT, NB1, E, cnt, dinv, n);
    scan_bsum<<<nb, T, 0, stream>>>(cnt, n, bsum);
    scan_carry<<<1, 1024, 0, stream>>>(bsum, nb);
    scan_emit<<<nb, T, 0, stream>>>(cnt, n, bsum, rowptr, 1);
    p2_scatter<<<NB1, T, 0, stream>>>(ebuf, scanned, NT, NB1, E, rowptr, csr_src, n);

    // ---- layer 1: 256 -> 32, relu ----  (gemm_reg: 128 rows/block)
    gemm_reg<256, 32><<<(n + 127) / 128, T, 0, stream>>>(x, W1, dinv, g1, n);
    spmm<32, true><<<((size_t)n * 32 + T - 1) / T, T, 0, stream>>>(rowptr, csr_src, g1, dinv, b1, a1, n);

    // ---- layer 2: 32 -> 64, relu ----  (gemm_reg: 64 rows/block)
    gemm_reg<32, 64><<<(n + 63) / 64, T, 0, stream>>>(a1, W2, dinv, g2, n);
    spmm<64, true><<<((size_t)n * 64 + T - 1) / T, T, 0, stream>>>(rowptr, csr_src, g2, dinv, b2, a2, n);

    // ---- layer 3: 64 -> 16, fused spmm + log_softmax ----  (gemm_reg: 256 rows/block)
    gemm_reg<64, 16><<<(n + 255) / 256, T, 0, stream>>>(a2, W3, dinv, g3, n);
    spmm16_ls<<<((size_t)n * 16 + T - 1) / T, T, 0, stream>>>(rowptr, csr_src, g3, dinv, b3, out, n);
}

// Round 10
// 509.065 us; speedup vs baseline: 9.8274x; 1.0430x over previous
//
#include <hip/hip_runtime.h>
#include <hip/hip_bf16.h>
#include <hip/hip_fp16.h>

// 3-layer GCN, CSR-gather formulation.
// CSR build = deterministic two-level counting sort (no contended global atomics).
// GEMMs = register-blocked 4x4 tiles, K-chunked, transposed-X LDS staging.
// Layers 1-2 store g=(X@W)*dinv as fp16 -> halves random-gather bytes in SpMM.

#define TILE 2048
#define EPT  8          // edges per thread = TILE/256
#define MAXB 512        // max coarse buckets (n <= 131072)

// ---------------- pass 1a: per-tile bucket histogram, coalesced [t][b] layout ----------------
__global__ __launch_bounds__(256) void hist2d_kernel(const int* __restrict__ dst, int E,
                                                     int NB1, int* __restrict__ histT) {
    __shared__ int h[MAXB];
    int t = blockIdx.x;
    for (int i = threadIdx.x; i < MAXB; i += 256) h[i] = 0;
    __syncthreads();
    int base = t * TILE;
    #pragma unroll
    for (int i = 0; i < EPT; ++i) {
        int e = base + threadIdx.x + i * 256;
        if (e < E) atomicAdd(&h[dst[e] >> 8], 1);
    }
    __syncthreads();
    for (int i = threadIdx.x; i < NB1; i += 256)
        histT[(size_t)t * NB1 + i] = h[i];
}

// ---------------- tiled transpose: histT[t][b] -> hist[b][t] ----------------
__global__ void transpose32(const int* __restrict__ in, int rows, int cols,
                            int* __restrict__ out) {
    __shared__ int tile[32][33];
    int c = blockIdx.x * 32 + threadIdx.x;
    int r = blockIdx.y * 32 + threadIdx.y;
    if (r < rows && c < cols) tile[threadIdx.y][threadIdx.x] = in[(size_t)r * cols + c];
    __syncthreads();
    int tr = blockIdx.x * 32 + threadIdx.y;   // output row (cols-dim)
    int tc = blockIdx.y * 32 + threadIdx.x;   // output col (rows-dim)
    if (tr < cols && tc < rows) out[(size_t)tr * rows + tc] = tile[threadIdx.x][threadIdx.y];
}

// ---------------- generic exclusive scan (3 kernels) ----------------
__global__ void scan_bsum(const int* __restrict__ in, int n, int* __restrict__ bsum) {
    __shared__ int s[256];
    int i = blockIdx.x * 256 + threadIdx.x;
    s[threadIdx.x] = (i < n) ? in[i] : 0;
    __syncthreads();
    for (int o = 128; o > 0; o >>= 1) {
        if (threadIdx.x < o) s[threadIdx.x] += s[threadIdx.x + o];
        __syncthreads();
    }
    if (threadIdx.x == 0) bsum[blockIdx.x] = s[0];
}

__global__ void scan_carry(int* __restrict__ bsum, int nb) {   // 1 block, 1024 thr, chunked
    __shared__ int s[1024];
    __shared__ int carry;
    if (threadIdx.x == 0) carry = 0;
    __syncthreads();
    for (int base = 0; base < nb; base += 1024) {
        int idx = base + threadIdx.x;
        int v = (idx < nb) ? bsum[idx] : 0;
        s[threadIdx.x] = v;
        __syncthreads();
        for (int o = 1; o < 1024; o <<= 1) {
            int t = (threadIdx.x >= o) ? s[threadIdx.x - o] : 0;
            __syncthreads();
            s[threadIdx.x] += t;
            __syncthreads();
        }
        if (idx < nb) bsum[idx] = carry + s[threadIdx.x] - v;   // exclusive
        __syncthreads();
        if (threadIdx.x == 0) carry += s[1023];
        __syncthreads();
    }
}

__global__ void scan_emit(const int* __restrict__ in, int n, const int* __restrict__ bsum,
                          int* __restrict__ out, int total) {
    __shared__ int s[256];
    int i = blockIdx.x * 256 + threadIdx.x;
    int v = (i < n) ? in[i] : 0;
    s[threadIdx.x] = v;
    __syncthreads();
    for (int o = 1; o < 256; o <<= 1) {
        int t = (threadIdx.x >= o) ? s[threadIdx.x - o] : 0;
        __syncthreads();
        s[threadIdx.x] += t;
        __syncthreads();
    }
    if (i < n) {
        int excl = bsum[blockIdx.x] + s[threadIdx.x] - v;
        out[i] = excl;
        if (total && i == n - 1) out[n] = excl + v;
    }
}

// ---------------- pass 1b: deterministic LDS-staged multi-split scatter ----------------
__global__ __launch_bounds__(256) void p1_scatter_tiled(const int* __restrict__ src,
                                                        const int* __restrict__ dst, int E,
                                                        int NB1, int NT,
                                                        const int* __restrict__ scanned,
                                                        int* __restrict__ ebuf) {
    __shared__ int h[MAXB], hb[MAXB], cur[MAXB], gb[MAXB];
    __shared__ int s2[256];
    __shared__ int stash[TILE];
    __shared__ unsigned short sb[TILE];
    const int t = blockIdx.x;
    for (int i = threadIdx.x; i < MAXB; i += 256) h[i] = 0;
    for (int i = threadIdx.x; i < NB1; i += 256)
        gb[i] = scanned[(size_t)i * NT + t];
    __syncthreads();
    const int base = t * TILE;
    int pk[EPT], cb[EPT];
    #pragma unroll
    for (int i = 0; i < EPT; ++i) {
        int e = base + threadIdx.x + i * 256;
        if (e < E) {
            int s = src[e], d = dst[e];
            pk[i] = (s << 8) | (d & 255);
            cb[i] = d >> 8;
            atomicAdd(&h[cb[i]], 1);
        } else cb[i] = -1;
    }
    __syncthreads();
    // exclusive scan of h[0..MAXB) with 256 threads (pair + Hillis-Steele)
    int a = h[2 * threadIdx.x], b2 = h[2 * threadIdx.x + 1];
    s2[threadIdx.x] = a + b2;
    __syncthreads();
    for (int o = 1; o < 256; o <<= 1) {
        int tv = (threadIdx.x >= o) ? s2[threadIdx.x - o] : 0;
        __syncthreads();
        s2[threadIdx.x] += tv;
        __syncthreads();
    }
    int excl2 = s2[threadIdx.x] - (a + b2);
    hb[2 * threadIdx.x]     = excl2;
    hb[2 * threadIdx.x + 1] = excl2 + a;
    cur[2 * threadIdx.x]     = excl2;
    cur[2 * threadIdx.x + 1] = excl2 + a;
    __syncthreads();
    // scatter tile into LDS, ordered by bucket
    #pragma unroll
    for (int i = 0; i < EPT; ++i) if (cb[i] >= 0) {
        int p = atomicAdd(&cur[cb[i]], 1);
        stash[p] = pk[i];
        sb[p] = (unsigned short)cb[i];
    }
    __syncthreads();
    // write out: per-bucket runs are contiguous in LDS and in global -> coalesced
    const int cnt_t = min(TILE, E - base);
    for (int j = threadIdx.x; j < cnt_t; j += 256) {
        int b = sb[j];
        ebuf[gb[b] + (j - hb[b])] = stash[j];
    }
}

// ---------------- pass 2a: per-bucket node histogram + dinv ----------------
__global__ __launch_bounds__(256) void p2_hist(const int* __restrict__ ebuf,
                                               const int* __restrict__ scanned, int NT, int NB1,
                                               int E, int* __restrict__ cnt,
                                               float* __restrict__ dinv, int n) {
    int b = blockIdx.x;
    __shared__ int h[256];
    h[threadIdx.x] = 0;
    __syncthreads();
    int beg = scanned[(size_t)b * NT];
    int end = (b + 1 < NB1) ? scanned[(size_t)(b + 1) * NT] : E;
    for (int i = beg + threadIdx.x; i < end; i += 256)
        atomicAdd(&h[ebuf[i] & 255], 1);
    __syncthreads();
    int node = b * 256 + threadIdx.x;
    if (node < n) {
        int v = h[threadIdx.x];
        cnt[node] = v;
        float x = 1.0f + (float)v;
        float r = rsqrtf(x);
        r = r * (1.5f - 0.5f * x * r * r);   // Newton refine to full f32 precision
        dinv[node] = r;
    }
}

// ---------------- pass 2b: LDS-cursor scatter into csr (bucket-local, single writer) ----------------
__global__ __launch_bounds__(256) void p2_scatter(const int* __restrict__ ebuf,
                                                  const int* __restrict__ scanned, int NT, int NB1,
                                                  int E, const int* __restrict__ rowptr,
                                                  int* __restrict__ csr_src, int n) {
    int b = blockIdx.x;
    __shared__ int cur[256];
    int node = b * 256 + threadIdx.x;
    cur[threadIdx.x] = (node < n) ? rowptr[node] : 0;
    __syncthreads();
    int beg = scanned[(size_t)b * NT];
    int end = (b + 1 < NB1) ? scanned[(size_t)(b + 1) * NT] : E;
    for (int i = beg + threadIdx.x; i < end; i += 256) {
        int v = ebuf[i];
        int p = atomicAdd(&cur[v & 255], 1);
        csr_src[p] = v >> 8;
    }
}

// ---------------- register-blocked GEMM: G = (X[n,FIN] @ W[FIN,FOUT]) * dinv[row] ----------------
// 256 threads; each thread owns a 4x4 output tile. K chunked by 32; X staged TRANSPOSED.
// HOUT: store output as fp16 (halves SpMM gather bytes) else fp32.
template<int FIN, int FOUT, bool HOUT>
__global__ __launch_bounds__(256) void gemm_reg(const float* __restrict__ X,
                                                const float* __restrict__ W,
                                                const float* __restrict__ dinv,
                                                void* __restrict__ Gv, int n) {
    constexpr int KC  = 32;
    constexpr int NCG = FOUT / 4;        // col-groups of 4
    constexpr int NRG = 256 / NCG;       // row-groups
    constexpr int R   = NRG * 4;         // rows per block
    constexpr int RL  = R + 4;           // Xt row length: %4==0 (b128-aligned), breaks pow2 stride
    __shared__ float Xt[KC][RL];
    __shared__ float Ws[KC][FOUT];

    const int row0 = blockIdx.x * R;
    const int cg = threadIdx.x % NCG;
    const int rg = threadIdx.x / NCG;
    const int r0 = rg * 4;

    float acc[4][4];
    #pragma unroll
    for (int i = 0; i < 4; ++i)
        #pragma unroll
        for (int j = 0; j < 4; ++j) acc[i][j] = 0.f;

    for (int kc = 0; kc < FIN; kc += KC) {
        constexpr int WF4 = KC * FOUT / 4;
        for (int i = threadIdx.x; i < WF4; i += 256)
            reinterpret_cast<float4*>(&Ws[0][0])[i] =
                reinterpret_cast<const float4*>(W + (size_t)kc * FOUT)[i];
        constexpr int XF4 = R * KC / 4;
        for (int i = threadIdx.x; i < XF4; i += 256) {
            int row = i / (KC / 4);
            int kq  = i % (KC / 4);
            int grow = row0 + row;
            float4 v = (grow < n)
                ? *reinterpret_cast<const float4*>(X + (size_t)grow * FIN + kc + kq * 4)
                : make_float4(0.f, 0.f, 0.f, 0.f);
            Xt[kq * 4 + 0][row] = v.x;
            Xt[kq * 4 + 1][row] = v.y;
            Xt[kq * 4 + 2][row] = v.z;
            Xt[kq * 4 + 3][row] = v.w;
        }
        __syncthreads();
        #pragma unroll
        for (int k = 0; k < KC; ++k) {
            const float4 xv = *reinterpret_cast<const float4*>(&Xt[k][r0]);
            const float4 wv = *reinterpret_cast<const float4*>(&Ws[k][cg * 4]);
            const float xr[4] = {xv.x, xv.y, xv.z, xv.w};
            const float wr[4] = {wv.x, wv.y, wv.z, wv.w};
            #pragma unroll
            for (int i = 0; i < 4; ++i)
                #pragma unroll
                for (int j = 0; j < 4; ++j)
                    acc[i][j] += xr[i] * wr[j];
        }
        __syncthreads();
    }
    #pragma unroll
    for (int i = 0; i < 4; ++i) {
        int grow = row0 + r0 + i;
        if (grow < n) {
            float di = dinv[grow];
            if (HOUT) {
                __half* Gh = (__half*)Gv;
                __half2 h01 = __floats2half2_rn(acc[i][0] * di, acc[i][1] * di);
                __half2 h23 = __floats2half2_rn(acc[i][2] * di, acc[i][3] * di);
                uint2 pk;
                pk.x = *reinterpret_cast<unsigned int*>(&h01);
                pk.y = *reinterpret_cast<unsigned int*>(&h23);
                *reinterpret_cast<uint2*>(Gh + (size_t)grow * FOUT + cg * 4) = pk;
            } else {
                float* G = (float*)Gv;
                float4 o = make_float4(acc[i][0] * di, acc[i][1] * di,
                                       acc[i][2] * di, acc[i][3] * di);
                *reinterpret_cast<float4*>(G + (size_t)grow * FOUT + cg * 4) = o;
            }
        }
    }
}

// ---------------- SpMM gather (fp16 g) + fused fp32 epilogue (layers 1,2) ----------------
template<int F, bool RELU>
__global__ void spmm_h(const int* __restrict__ rowptr, const int* __restrict__ csr_src,
                       const __half* __restrict__ g, const float* __restrict__ dinv,
                       const float* __restrict__ b, float* __restrict__ out, int n) {
    int gi = blockIdx.x * blockDim.x + threadIdx.x;
    int node = gi / F;
    int lane = gi % F;
    if (node >= n) return;
    int beg = rowptr[node], end = rowptr[node + 1];
    float acc = 0.f;
    int j = beg;
    for (; j + 3 < end; j += 4) {          // 4 independent gathers in flight
        int s0 = csr_src[j], s1 = csr_src[j + 1], s2 = csr_src[j + 2], s3 = csr_src[j + 3];
        acc += __half2float(g[(size_t)s0 * F + lane]);
        acc += __half2float(g[(size_t)s1 * F + lane]);
        acc += __half2float(g[(size_t)s2 * F + lane]);
        acc += __half2float(g[(size_t)s3 * F + lane]);
    }
    for (; j < end; ++j) acc += __half2float(g[(size_t)csr_src[j] * F + lane]);
    float v = dinv[node] * (acc + __half2float(g[(size_t)node * F + lane])) + b[lane];
    if (RELU) v = fmaxf(v, 0.f);
    out[(size_t)node * F + lane] = v;
}

// ---------------- layer 3: SpMM(F=16, fp32 g) + bias + log_softmax fused ----------------
__global__ void spmm16_ls(const int* __restrict__ rowptr, const int* __restrict__ csr_src,
                          const float* __restrict__ g, const float* __restrict__ dinv,
                          const float* __restrict__ b, float* __restrict__ out, int n) {
    int gi = blockIdx.x * blockDim.x + threadIdx.x;
    int node = gi >> 4;
    int lane = gi & 15;
    if (node >= n) return;
    int beg = rowptr[node], end = rowptr[node + 1];
    float acc = 0.f;
    int j = beg;
    for (; j + 3 < end; j += 4) {
        int s0 = csr_src[j], s1 = csr_src[j + 1], s2 = csr_src[j + 2], s3 = csr_src[j + 3];
        acc += g[(size_t)s0 * 16 + lane];
        acc += g[(size_t)s1 * 16 + lane];
        acc += g[(size_t)s2 * 16 + lane];
        acc += g[(size_t)s3 * 16 + lane];
    }
    for (; j < end; ++j) acc += g[(size_t)csr_src[j] * 16 + lane];
    float v = dinv[node] * (acc + g[(size_t)node * 16 + lane]) + b[lane];
    float m = v;
    #pragma unroll
    for (int o = 1; o < 16; o <<= 1) m = fmaxf(m, __shfl_xor(m, o, 64));
    float e = __expf(v - m);
    float ssum = e;
    #pragma unroll
    for (int o = 1; o < 16; o <<= 1) ssum += __shfl_xor(ssum, o, 64);
    out[(size_t)node * 16 + lane] = v - m - __logf(ssum);
}

extern "C" void kernel_launch(void* const* d_in, const int* in_sizes, int n_in,
                              void* d_out, int out_size, void* d_ws, size_t ws_size,
                              hipStream_t stream) {
    const float* x  = (const float*)d_in[0];
    const int*   ei = (const int*)d_in[1];
    const float* W1 = (const float*)d_in[2];
    const float* b1 = (const float*)d_in[3];
    const float* W2 = (const float*)d_in[4];
    const float* b2 = (const float*)d_in[5];
    const float* W3 = (const float*)d_in[6];
    const float* b3 = (const float*)d_in[7];
    float* out = (float*)d_out;

    const int n = in_sizes[0] / 256;     // 100000
    const int E = in_sizes[1] / 2;       // 3200000
    const int* src = ei;
    const int* dst = ei + E;

    const int NP  = ((n + 256) + 255) / 256 * 256;   // padded node slots (>= n+1)
    const int NB1 = (n + 255) / 256;                 // coarse buckets (391)
    const int NT  = (E + TILE - 1) / TILE;           // tiles (1563)
    const int M   = NB1 * NT;                        // 2-D hist size (~611K)

    // workspace layout (4-byte units; regions identical to round 8)
    int*   cnt     = (int*)d_ws;               // NP
    int*   rowptr  = cnt + NP;                 // NP (n+1 used)
    int*   bsum    = rowptr + NP;              // 512
    int*   bsum2   = bsum + 512;               // 4096
    float* dinv    = (float*)(bsum2 + 4096);   // NP
    int*   csr_src = (int*)(dinv + NP);        // E
    float* g1f     = (float*)(csr_src + E);    // region n*32 floats (used as n*32 halves)
    float* a1      = g1f + (size_t)n * 32;     // n*32
    float* g2f     = a1 + (size_t)n * 32;      // region n*64 floats (used as n*64 halves)
    float* a2      = g2f + (size_t)n * 64;     // n*64
    __half* g1     = (__half*)g1f;             // n*32 halves
    __half* g2     = (__half*)g2f;             // n*64 halves
    float* g3      = g1f;                      // n*16 fp32 (reuse of g1 region)
    int*   ebuf    = (int*)g1f;                // E ints (dead before gemm1)
    int*   histT   = (int*)g2f;                // M ints (dead before gemm2)
    int*   hist2d  = histT + ((M + 255) & ~255);   // M ints
    int*   scanned = (int*)a2;                 // M ints (dead before spmm<64>)

    const int T = 256;
    const int nb  = (n + 255) / 256;
    const int MB  = (M + 255) / 256;

    // ---- pass 1: 2-D histogram -> transpose -> scan -> deterministic scatter ----
    hist2d_kernel<<<NT, T, 0, stream>>>(dst, E, NB1, histT);
    transpose32<<<dim3((NB1 + 31) / 32, (NT + 31) / 32), dim3(32, 32), 0, stream>>>(
        histT, NT, NB1, hist2d);
    scan_bsum<<<MB, T, 0, stream>>>(hist2d, M, bsum2);
    scan_carry<<<1, 1024, 0, stream>>>(bsum2, MB);
    scan_emit<<<MB, T, 0, stream>>>(hist2d, M, bsum2, scanned, 0);
    p1_scatter_tiled<<<NT, T, 0, stream>>>(src, dst, E, NB1, NT, scanned, ebuf);

    // ---- pass 2: per-bucket hist (+dinv) -> node scan -> csr scatter ----
    p2_hist<<<NB1, T, 0, stream>>>(ebuf, scanned, NT, NB1, E, cnt, dinv, n);
    scan_bsum<<<nb, T, 0, stream>>>(cnt, n, bsum);
    scan_carry<<<1, 1024, 0, stream>>>(bsum, nb);
    scan_emit<<<nb, T, 0, stream>>>(cnt, n, bsum, rowptr, 1);
    p2_scatter<<<NB1, T, 0, stream>>>(ebuf, scanned, NT, NB1, E, rowptr, csr_src, n);

    // ---- layer 1: 256 -> 32, relu ----  (g1 fp16)
    gemm_reg<256, 32, true><<<(n + 127) / 128, T, 0, stream>>>(x, W1, dinv, (void*)g1, n);
    spmm_h<32, true><<<((size_t)n * 32 + T - 1) / T, T, 0, stream>>>(rowptr, csr_src, g1, dinv, b1, a1, n);

    // ---- layer 2: 32 -> 64, relu ----  (g2 fp16)
    gemm_reg<32, 64, true><<<(n + 63) / 64, T, 0, stream>>>(a1, W2, dinv, (void*)g2, n);
    spmm_h<64, true><<<((size_t)n * 64 + T - 1) / T, T, 0, stream>>>(rowptr, csr_src, g2, dinv, b2, a2, n);

    // ---- layer 3: 64 -> 16, fused spmm + log_softmax ----  (g3 fp32: 64B row = 1 line)
    gemm_reg<64, 16, false><<<(n + 255) / 256, T, 0, stream>>>(a2, W3, dinv, (void*)g3, n);
    spmm16_ls<<<((size_t)n * 16 + T - 1) / T, T, 0, stream>>>(rowptr, csr_src, g3, dinv, b3, out, n);
}